// Round 11
// baseline (143.618 us; speedup 1.0000x reference)
//
#include <hip/hip_runtime.h>
#include <hip/hip_fp16.h>

// SJLT projection: y[b, idx[d,j]] += sign[d,j] * x[b,d]; y *= 0.5
// B=4096, D=16384, P=1024, C=4.
//
// Round-11: geometry designed to fit the 64-VGPR / 32-waves-per-CU tier.
//  - CHUNK_D=1024, NCHUNK=16: each thread stages ONE scalar d per chunk
//    (pv = 8 floats per depth), one granule ds_write_b128 per chunk.
//    LDS = 2 x 16 KiB = 32 KiB/block -> occupancy capped only by VGPR:
//    <=64 VGPR gives 2 x 1024-thr blocks/CU = 32 waves (vs 16 in r5-r10).
//  - persistent regs ~46 (pv 16, lists 14, accf 8, addr ~8), peak ~60-64.
//    __launch_bounds__(1024,8) sets the 64-VGPR cap. r8/r9 failed this
//    tier with ~75 demand; this geometry actually fits.
//  - lambda=4 per (chunk,col) list: fixed dummy-padded head-8 (uint4) +
//    checked entries 8-11 (uint2 vs DUMMY) + lazy deep tail n>12
//    (~0.09%/lane) from L2 with exact count. LCAP=24 (48 B stride, 16B
//    aligned). Depth-2 x prefetch kept (pv ping-pong by chunk parity).
//  - unchanged: fp16 granules [d][8 rows] 16 B, XOR write swizzle
//    (conflict-free), 1 barrier/chunk, full unroll, per-chunk f16
//    accumulators flushed to f32.

#define BATCH     4096
#define ORIG_DIM  16384
#define PROJ_DIM  1024
#define NCHUNK    16
#define CHUNK_D   1024
#define ROWS      8
#define LCAP      24         // entries per list; P(n>24 | lam=4) ~ 1e-12
#define NLISTS    (NCHUNK * PROJ_DIM)        // 16384
#define DUMMY_W   0x00020002u                // two e=2 entries (zero-flag)

// ws layout (bytes):
//   0      : int flag (1 if rand_indices is int64)
//   64     : int    cnt[NLISTS]              (65536 B)
//   65600  : ushort entry[NLISTS*LCAP]       (786432 B)
#define WS_CNT_I   16
#define WS_ENT_B   65600
#define WS_NEEDED  (65600 + 786432)

typedef _Float16 h16x2 __attribute__((ext_vector_type(2)));

__global__ void k_init(const unsigned int* __restrict__ idx32,
                       int* __restrict__ ws_i,
                       uint4* __restrict__ ent4) {
    int t = blockIdx.x * 256 + threadIdx.x;        // 16384 threads, 1/list
    ent4[3 * t]     = uint4{DUMMY_W, DUMMY_W, DUMMY_W, DUMMY_W};
    ent4[3 * t + 1] = uint4{DUMMY_W, DUMMY_W, DUMMY_W, DUMMY_W};
    ent4[3 * t + 2] = uint4{DUMMY_W, DUMMY_W, DUMMY_W, DUMMY_W};
    ws_i[WS_CNT_I + t] = 0;
    if (blockIdx.x == 0 && threadIdx.x < 64) {
        unsigned int v = idx32[2 * threadIdx.x + 1];
        unsigned long long b = __ballot(v == 0u);
        if (threadIdx.x == 0) ws_i[0] = (b == 0xFFFFFFFFFFFFFFFFull) ? 1 : 0;
    }
}

__global__ void k_fill(const unsigned int* __restrict__ idx32,
                       const int* __restrict__ signs,
                       int* __restrict__ ws_i,
                       unsigned short* __restrict__ entry) {
    int t = blockIdx.x * 256 + threadIdx.x;        // 0..65535 == d*4 + j
    int flag64 = ws_i[0];
    unsigned int p = (flag64 ? idx32[2 * t] : idx32[t]) & (PROJ_DIM - 1);
    int d  = t >> 2;
    unsigned int sg = (signs[t] < 0) ? 1u : 0u;
    int chunk = d >> 10;
    int dl = d & (CHUNK_D - 1);
    unsigned int slot = (unsigned int)dl ^ (((unsigned int)dl >> 3) & 7u);
    unsigned short e = (unsigned short)((slot << 2) | sg);   // zero-flag = 0
    int base = chunk * PROJ_DIM + (int)p;
    int pos = atomicAdd(&ws_i[WS_CNT_I + base], 1);
    if (pos < LCAP)
        entry[(size_t)base * LCAP + pos] = e;
}

// process one entry E (8 rows via 4x v_pk_fma_f16)
#define PROC1(E) { \
    unsigned int _e = (unsigned int)(E); \
    uint4 _q = xsb[_e >> 2]; \
    unsigned int _s = (_e & 2u) ? 0u \
                    : ((_e & 1u) ? 0xBC00BC00u : 0x3C003C00u); \
    h16x2 _sp = __builtin_bit_cast(h16x2, _s); \
    ha0 = __builtin_elementwise_fma(__builtin_bit_cast(h16x2, _q.x), _sp, ha0); \
    ha1 = __builtin_elementwise_fma(__builtin_bit_cast(h16x2, _q.y), _sp, ha1); \
    ha2 = __builtin_elementwise_fma(__builtin_bit_cast(h16x2, _q.z), _sp, ha2); \
    ha3 = __builtin_elementwise_fma(__builtin_bit_cast(h16x2, _q.w), _sp, ha3); }

#define PROC2(W) { PROC1((W) & 0xffffu); PROC1((W) >> 16); }

__launch_bounds__(1024, 8)
__global__ void k_main(const float* __restrict__ x,
                       const int* __restrict__ cnt,
                       const unsigned short* __restrict__ entry,
                       float* __restrict__ y) {
    __shared__ uint4 xs[2][CHUNK_D];     // 2 x 16 KiB, fp16 granules [d][8 rows]
    const int tid = threadIdx.x;         // 0..1023  == column == staged d
    const int b0  = blockIdx.x * ROWS;

    // this thread stages scalar element d = tid of each chunk, all 8 rows
    const float* xp = x + (size_t)b0 * ORIG_DIM + tid;

    uint4 pf_h0[2];      // entries 0..7
    uint2 pf_t [2];      // entries 8..11 (checked vs DUMMY)
    int   nn   [2];      // list count
    float pv[2][ROWS];   // depth-2 x prefetch (ping-pong by chunk parity)

    // ---- prologue: lists(ch0), x(ch0) -> pv[0], x(ch1) -> pv[1] ----
    {
        const unsigned short* lp = entry + (size_t)tid * LCAP;
        pf_h0[0] = *(const uint4*)lp;
        pf_t [0] = *(const uint2*)(lp + 8);
        nn   [0] = cnt[tid];
    }
    #pragma unroll
    for (int r = 0; r < ROWS; ++r)
        pv[0][r] = xp[(size_t)r * ORIG_DIM];
    #pragma unroll
    for (int r = 0; r < ROWS; ++r)
        pv[1][r] = xp[CHUNK_D + (size_t)r * ORIG_DIM];

    float accf[ROWS];
    #pragma unroll
    for (int r = 0; r < ROWS; ++r) accf[r] = 0.f;

    #pragma unroll
    for (int ch = 0; ch < NCHUNK; ++ch) {
        const int cur = ch & 1;
        uint4* xsb = xs[cur];

        // ---- pack 1 granule (fp16 RTZ) & ds_write_b128, swizzled ----
        {
            uint4 w;
            w.x = __builtin_bit_cast(unsigned int, __builtin_amdgcn_cvt_pkrtz(pv[cur][0], pv[cur][1]));
            w.y = __builtin_bit_cast(unsigned int, __builtin_amdgcn_cvt_pkrtz(pv[cur][2], pv[cur][3]));
            w.z = __builtin_bit_cast(unsigned int, __builtin_amdgcn_cvt_pkrtz(pv[cur][4], pv[cur][5]));
            w.w = __builtin_bit_cast(unsigned int, __builtin_amdgcn_cvt_pkrtz(pv[cur][6], pv[cur][7]));
            xsb[tid ^ ((tid >> 3) & 7)] = w;
        }

        // ---- issue prefetches: lists(ch+1), x(ch+2) into freed pv[cur] ----
        if (ch + 1 < NCHUNK) {
            const int nxt = (ch + 1) & 1;
            const int base = (ch + 1) * PROJ_DIM + tid;
            const unsigned short* lp = entry + (size_t)base * LCAP;
            pf_h0[nxt] = *(const uint4*)lp;
            pf_t [nxt] = *(const uint2*)(lp + 8);
            nn   [nxt] = cnt[base];
        }
        if (ch + 2 < NCHUNK) {
            const float* xq = xp + (size_t)(ch + 2) * CHUNK_D;
            #pragma unroll
            for (int r = 0; r < ROWS; ++r)
                pv[cur][r] = xq[(size_t)r * ORIG_DIM];
        }

        __syncthreads();

        // ---- gather: fixed head-8, checked 8-11, rare deep tail ----
        h16x2 ha0{0,0}, ha1{0,0}, ha2{0,0}, ha3{0,0};
        {
            uint4 h0 = pf_h0[cur];
            uint2 t  = pf_t [cur];
            int   n  = nn   [cur];
            PROC2(h0.x); PROC2(h0.y); PROC2(h0.z); PROC2(h0.w);
            if (t.x != DUMMY_W) { PROC2(t.x); }
            if (t.y != DUMMY_W) { PROC2(t.y); }
            if (n > 12) {        // deep tail, ~0.09%/lane: lazy exact L2 reads
                int wm = (n + 1) >> 1;
                int we = wm < 12 ? wm : 12;
                const unsigned int* dp = (const unsigned int*)
                    (entry + ((size_t)(ch * PROJ_DIM) + tid) * LCAP);
                for (int w = 6; w < we; ++w) { unsigned int wd = dp[w]; PROC2(wd); }
            }
        }

        // ---- flush fp16 pair-accumulators into fp32 ----
        accf[0] += (float)ha0[0]; accf[1] += (float)ha0[1];
        accf[2] += (float)ha1[0]; accf[3] += (float)ha1[1];
        accf[4] += (float)ha2[0]; accf[5] += (float)ha2[1];
        accf[6] += (float)ha3[0]; accf[7] += (float)ha3[1];
    }

    // ---- epilogue: y = acc * 1/sqrt(4), coalesced (col = tid) ----
    float* yb = y + (size_t)b0 * PROJ_DIM + tid;
    #pragma unroll
    for (int r = 0; r < ROWS; ++r)
        yb[(size_t)r * PROJ_DIM] = accf[r] * 0.5f;
}

// Fallback if workspace is too small: per-row LDS atomic scatter.
__global__ void k_fallback(const float* __restrict__ x,
                           const unsigned int* __restrict__ idx32,
                           const int* __restrict__ signs,
                           float* __restrict__ y) {
    __shared__ float ys[PROJ_DIM];
    __shared__ int sflag;
    int tid = threadIdx.x;
    int b = blockIdx.x;
    if (tid < 64) {
        unsigned int v = idx32[2 * tid + 1];
        unsigned long long bl = __ballot(v == 0u);
        if (tid == 0) sflag = (bl == 0xFFFFFFFFFFFFFFFFull) ? 1 : 0;
    }
    for (int i = tid; i < PROJ_DIM; i += 256) ys[i] = 0.0f;
    __syncthreads();
    int f = sflag;
    const float* xr = x + (size_t)b * ORIG_DIM;
    for (int d = tid; d < ORIG_DIM; d += 256) {
        float v = xr[d];
        #pragma unroll
        for (int j = 0; j < 4; ++j) {
            int t = d * 4 + j;
            unsigned int p = (f ? idx32[2 * t] : idx32[t]) & (PROJ_DIM - 1);
            atomicAdd(&ys[p], (signs[t] < 0) ? -v : v);
        }
    }
    __syncthreads();
    for (int i = tid; i < PROJ_DIM; i += 256)
        y[(size_t)b * PROJ_DIM + i] = ys[i] * 0.5f;
}

extern "C" void kernel_launch(void* const* d_in, const int* in_sizes, int n_in,
                              void* d_out, int out_size, void* d_ws, size_t ws_size,
                              hipStream_t stream) {
    const float*        x     = (const float*)d_in[0];
    const unsigned int* idx32 = (const unsigned int*)d_in[1];
    const int*          signs = (const int*)d_in[2];
    float*              y     = (float*)d_out;

    if (ws_size >= (size_t)WS_NEEDED) {
        int* ws_i = (int*)d_ws;
        unsigned short* entry = (unsigned short*)((char*)d_ws + WS_ENT_B);
        k_init<<<64, 256, 0, stream>>>(idx32, ws_i, (uint4*)entry);
        k_fill<<<(ORIG_DIM * 4) / 256, 256, 0, stream>>>(idx32, signs, ws_i, entry);
        k_main<<<BATCH / ROWS, 1024, 0, stream>>>(x, ws_i + WS_CNT_I, entry, y);
    } else {
        k_fallback<<<BATCH, 256, 0, stream>>>(x, idx32, signs, y);
    }
}

// Round 12
// 74.346 us; speedup vs baseline: 1.9317x; 1.9317x over previous
//
#include <hip/hip_runtime.h>
#include <hip/hip_fp16.h>

// SJLT projection: y[b, idx[d,j]] += sign[d,j] * x[b,d]; y *= 0.5
// B=4096, D=16384, P=1024, C=4.
//
// Round-12: lambda=8 work level + genuine 64-VGPR fit -> 2 blocks/CU.
//  - tables identical to r10 (CHUNK_D=2048, NCHUNK=8, LCAP=32): the
//    proven-lowest gather work level. r11's regression bundled lambda=4
//    (+60% gather work) with the occupancy gain; this isolates occupancy.
//  - register diet: depth-1 x prefetch (pv 8xfloat2; cross-block TLP now
//    covers the pack stall instead of depth-2 ILP), fp16 accumulators
//    persistent across all 8 chunks (4 regs vs 8+flush; +~0.07 error vs
//    0.48 threshold). Persistent ~44 VGPR, peak ~56 -> fits
//    __launch_bounds__(1024,8)'s 64-VGPR cap without AGPR shuffling.
//  - 2 x 1024-thr blocks/CU = 32 waves: block B's gather overlaps block
//    A's pack-vmcnt stall (the phase convoy that pinned r5/r10 at 83us).
//  - unchanged: fp16 granules [d][8 rows] 16 B, XOR-swizzled staging
//    writes, 1 barrier/chunk, straight-line head-12 + checked words 6..7
//    + lazy deep tail (n>16) from L2.

#define BATCH     4096
#define ORIG_DIM  16384
#define PROJ_DIM  1024
#define NCHUNK    8
#define CHUNK_D   2048
#define ROWS      8
#define LCAP      32
#define NLISTS    (NCHUNK * PROJ_DIM)        // 8192
#define DUMMY_W   0x00020002u                // two e=2 entries (zero-flag)

// ws layout (bytes):
//   0      : int flag (1 if rand_indices is int64)
//   64     : int    cnt[NLISTS]              (32768 B)
//   32832  : ushort entry[NLISTS*LCAP]       (524288 B)
#define WS_CNT_I   16
#define WS_ENT_B   32832
#define WS_NEEDED  (32832 + 524288)

typedef _Float16 h16x2 __attribute__((ext_vector_type(2)));

__global__ void k_init(const unsigned int* __restrict__ idx32,
                       int* __restrict__ ws_i,
                       uint4* __restrict__ ent4) {
    int t = blockIdx.x * 256 + threadIdx.x;        // 16384 threads
    ent4[2 * t]     = uint4{DUMMY_W, DUMMY_W, DUMMY_W, DUMMY_W};
    ent4[2 * t + 1] = uint4{DUMMY_W, DUMMY_W, DUMMY_W, DUMMY_W};
    if (t < NLISTS / 2)
        ((int2*)(ws_i + WS_CNT_I))[t] = int2{0, 0};
    if (blockIdx.x == 0 && threadIdx.x < 64) {
        unsigned int v = idx32[2 * threadIdx.x + 1];
        unsigned long long b = __ballot(v == 0u);
        if (threadIdx.x == 0) ws_i[0] = (b == 0xFFFFFFFFFFFFFFFFull) ? 1 : 0;
    }
}

__global__ void k_fill(const unsigned int* __restrict__ idx32,
                       const int* __restrict__ signs,
                       int* __restrict__ ws_i,
                       unsigned short* __restrict__ entry) {
    int t = blockIdx.x * 256 + threadIdx.x;        // 0..65535 == d*4 + j
    int flag64 = ws_i[0];
    unsigned int p = (flag64 ? idx32[2 * t] : idx32[t]) & (PROJ_DIM - 1);
    int d  = t >> 2;
    unsigned int sg = (signs[t] < 0) ? 1u : 0u;
    int chunk = d >> 11;
    int dl = d & (CHUNK_D - 1);
    unsigned int slot = (unsigned int)dl ^ (((unsigned int)dl >> 3) & 7u);
    unsigned short e = (unsigned short)((slot << 2) | sg);   // zero-flag = 0
    int base = chunk * PROJ_DIM + (int)p;
    int pos = atomicAdd(&ws_i[WS_CNT_I + base], 1);
    if (pos < LCAP)
        entry[(size_t)base * LCAP + pos] = e;
}

// process one entry E (8 rows via 4x v_pk_fma_f16) into persistent ha0..ha3
#define PROC1(E) { \
    unsigned int _e = (unsigned int)(E); \
    uint4 _q = xsb[_e >> 2]; \
    unsigned int _s = (_e & 2u) ? 0u \
                    : ((_e & 1u) ? 0xBC00BC00u : 0x3C003C00u); \
    h16x2 _sp = __builtin_bit_cast(h16x2, _s); \
    ha0 = __builtin_elementwise_fma(__builtin_bit_cast(h16x2, _q.x), _sp, ha0); \
    ha1 = __builtin_elementwise_fma(__builtin_bit_cast(h16x2, _q.y), _sp, ha1); \
    ha2 = __builtin_elementwise_fma(__builtin_bit_cast(h16x2, _q.z), _sp, ha2); \
    ha3 = __builtin_elementwise_fma(__builtin_bit_cast(h16x2, _q.w), _sp, ha3); }

#define PROC2(W) { PROC1((W) & 0xffffu); PROC1((W) >> 16); }

__launch_bounds__(1024, 8)
__global__ void k_main(const float* __restrict__ x,
                       const int* __restrict__ cnt,
                       const unsigned short* __restrict__ entry,
                       float* __restrict__ y) {
    __shared__ uint4 xs[2][CHUNK_D];     // 2 x 32 KiB, fp16 granules [d][8 rows]
    const int tid = threadIdx.x;         // 0..1023  == column
    const int b0  = blockIdx.x * ROWS;

    // this thread stages d-pair {2*tid, 2*tid+1} of each chunk
    const float* xp = x + (size_t)b0 * ORIG_DIM + tid * 2;

    uint4 pf_h0[2];      // head words 0..3  (entries 0..7)
    uint2 pf_h1[2];      // head words 4..5  (entries 8..11)
    uint2 pf_t [2];      // tail words 6..7  (entries 12..15)
    int   nn   [2];      // list count
    float2 pv[ROWS];     // depth-1 x prefetch (TLP across 2 blocks/CU hides)

    // ---- prologue: lists(ch0) + x(ch0) ----
    {
        const unsigned short* lp = entry + (size_t)tid * LCAP;
        pf_h0[0] = *(const uint4*)lp;
        pf_h1[0] = *(const uint2*)(lp + 8);
        pf_t [0] = *(const uint2*)(lp + 12);
        nn   [0] = cnt[tid];
    }
    #pragma unroll
    for (int r = 0; r < ROWS; ++r)
        pv[r] = *(const float2*)(xp + (size_t)r * ORIG_DIM);

    // persistent fp16 pair-accumulators (all chunks; flushed at epilogue)
    h16x2 ha0{0,0}, ha1{0,0}, ha2{0,0}, ha3{0,0};

    #pragma unroll
    for (int ch = 0; ch < NCHUNK; ++ch) {
        const int cur = ch & 1;
        uint4* xsb = xs[cur];

        // ---- pack 2 granules (fp16 RTZ) & ds_write_b128, swizzled ----
        // (vmcnt wait for pv lands here; other block on CU keeps pipes fed)
        {
            int dl0 = tid * 2;
            int dl1 = dl0 + 1;
            uint4 w0, w1;
            w0.x = __builtin_bit_cast(unsigned int, __builtin_amdgcn_cvt_pkrtz(pv[0].x, pv[1].x));
            w0.y = __builtin_bit_cast(unsigned int, __builtin_amdgcn_cvt_pkrtz(pv[2].x, pv[3].x));
            w0.z = __builtin_bit_cast(unsigned int, __builtin_amdgcn_cvt_pkrtz(pv[4].x, pv[5].x));
            w0.w = __builtin_bit_cast(unsigned int, __builtin_amdgcn_cvt_pkrtz(pv[6].x, pv[7].x));
            w1.x = __builtin_bit_cast(unsigned int, __builtin_amdgcn_cvt_pkrtz(pv[0].y, pv[1].y));
            w1.y = __builtin_bit_cast(unsigned int, __builtin_amdgcn_cvt_pkrtz(pv[2].y, pv[3].y));
            w1.z = __builtin_bit_cast(unsigned int, __builtin_amdgcn_cvt_pkrtz(pv[4].y, pv[5].y));
            w1.w = __builtin_bit_cast(unsigned int, __builtin_amdgcn_cvt_pkrtz(pv[6].y, pv[7].y));
            xsb[dl0 ^ ((dl0 >> 3) & 7)] = w0;
            xsb[dl1 ^ ((dl1 >> 3) & 7)] = w1;
        }

        // ---- issue NEXT chunk's prefetches (lists, then x into pv) ----
        // (in-order issue: pack already read pv, so reusing regs is safe)
        if (ch + 1 < NCHUNK) {
            const int nxt = (ch + 1) & 1;
            const int base = (ch + 1) * PROJ_DIM + tid;
            const unsigned short* lp = entry + (size_t)base * LCAP;
            pf_h0[nxt] = *(const uint4*)lp;
            pf_h1[nxt] = *(const uint2*)(lp + 8);
            pf_t [nxt] = *(const uint2*)(lp + 12);
            nn   [nxt] = cnt[base];
            const float* xq = xp + (size_t)(ch + 1) * CHUNK_D;
            #pragma unroll
            for (int r = 0; r < ROWS; ++r)
                pv[r] = *(const float2*)(xq + (size_t)r * ORIG_DIM);
        }

        __syncthreads();

        // ---- gather from registers: straight-line head, checked tail ----
        {
            uint4 h0 = pf_h0[cur];
            uint2 h1 = pf_h1[cur];
            uint2 t  = pf_t [cur];
            int   n  = nn   [cur];
            PROC2(h0.x); PROC2(h0.y); PROC2(h0.z); PROC2(h0.w);
            PROC2(h1.x); PROC2(h1.y);
            if (t.x != DUMMY_W) { PROC2(t.x); }
            if (t.y != DUMMY_W) { PROC2(t.y); }
            if (n > 16) {        // deep tail, 0.37%/lane: lazy exact L2 reads
                int wm = (n + 1) >> 1;
                int we = wm < 16 ? wm : 16;
                const unsigned int* dp = (const unsigned int*)
                    (entry + ((size_t)(ch * PROJ_DIM) + tid) * LCAP);
                for (int w = 8; w < we; ++w) { unsigned int wd = dp[w]; PROC2(wd); }
            }
        }
    }

    // ---- epilogue: y = acc * 1/sqrt(4), coalesced (col = tid) ----
    float* yb = y + (size_t)b0 * PROJ_DIM + tid;
    yb[0 * PROJ_DIM] = (float)ha0[0] * 0.5f;
    yb[1 * PROJ_DIM] = (float)ha0[1] * 0.5f;
    yb[2 * PROJ_DIM] = (float)ha1[0] * 0.5f;
    yb[3 * PROJ_DIM] = (float)ha1[1] * 0.5f;
    yb[4 * PROJ_DIM] = (float)ha2[0] * 0.5f;
    yb[5 * PROJ_DIM] = (float)ha2[1] * 0.5f;
    yb[6 * PROJ_DIM] = (float)ha3[0] * 0.5f;
    yb[7 * PROJ_DIM] = (float)ha3[1] * 0.5f;
}

// Fallback if workspace is too small: per-row LDS atomic scatter.
__global__ void k_fallback(const float* __restrict__ x,
                           const unsigned int* __restrict__ idx32,
                           const int* __restrict__ signs,
                           float* __restrict__ y) {
    __shared__ float ys[PROJ_DIM];
    __shared__ int sflag;
    int tid = threadIdx.x;
    int b = blockIdx.x;
    if (tid < 64) {
        unsigned int v = idx32[2 * tid + 1];
        unsigned long long bl = __ballot(v == 0u);
        if (tid == 0) sflag = (bl == 0xFFFFFFFFFFFFFFFFull) ? 1 : 0;
    }
    for (int i = tid; i < PROJ_DIM; i += 256) ys[i] = 0.0f;
    __syncthreads();
    int f = sflag;
    const float* xr = x + (size_t)b * ORIG_DIM;
    for (int d = tid; d < ORIG_DIM; d += 256) {
        float v = xr[d];
        #pragma unroll
        for (int j = 0; j < 4; ++j) {
            int t = d * 4 + j;
            unsigned int p = (f ? idx32[2 * t] : idx32[t]) & (PROJ_DIM - 1);
            atomicAdd(&ys[p], (signs[t] < 0) ? -v : v);
        }
    }
    __syncthreads();
    for (int i = tid; i < PROJ_DIM; i += 256)
        y[(size_t)b * PROJ_DIM + i] = ys[i] * 0.5f;
}

extern "C" void kernel_launch(void* const* d_in, const int* in_sizes, int n_in,
                              void* d_out, int out_size, void* d_ws, size_t ws_size,
                              hipStream_t stream) {
    const float*        x     = (const float*)d_in[0];
    const unsigned int* idx32 = (const unsigned int*)d_in[1];
    const int*          signs = (const int*)d_in[2];
    float*              y     = (float*)d_out;

    if (ws_size >= (size_t)WS_NEEDED) {
        int* ws_i = (int*)d_ws;
        unsigned short* entry = (unsigned short*)((char*)d_ws + WS_ENT_B);
        k_init<<<64, 256, 0, stream>>>(idx32, ws_i, (uint4*)entry);
        k_fill<<<(ORIG_DIM * 4) / 256, 256, 0, stream>>>(idx32, signs, ws_i, entry);
        k_main<<<BATCH / ROWS, 1024, 0, stream>>>(x, ws_i + WS_CNT_I, entry, y);
    } else {
        k_fallback<<<BATCH, 256, 0, stream>>>(x, idx32, signs, y);
    }
}